// Round 13
// baseline (286.945 us; speedup 1.0000x reference)
//
#include <hip/hip_runtime.h>
#include <cstdint>
#include <cstddef>

#define NN 100000
#define NE 1600000
#define F  128
#define NPAD 100352          // 98 * 1024
#define NBUCK 3125           // NN / 32 fine buckets of 32 nodes (gather granularity)
#define BCAPG 768            // fine bucket capacity (mean 512, +11 sd)
#define NFILL 768            // fill-role blocks
#define CHUNK 2084           // ceil(NE / NFILL)
#define NGEMM 768            // gemm-role blocks (grid 1536, 6/CU resident)
#define GSTRIDE 16           // cursor padding: one counter per 64B line
#define NREG 49              // coarse regions (2048 nodes each)
#define RCAP 36864           // region capacity (mean ~32650, +23 sd)
#define P2SPLIT 16           // pass-2 sort blocks per region
#define P2J 17               // + 1 deg-histogram block per region
#define P2MAX 2304           // ceil(RCAP / P2SPLIT)

typedef __attribute__((ext_vector_type(8))) short bf16x8;
typedef __attribute__((ext_vector_type(4))) float f32x4;

// bf16 helpers (RNE)
__device__ __forceinline__ unsigned short f2bf(float f) {
    unsigned u = __float_as_uint(f);
    unsigned r = (u + 0x7fffu + ((u >> 16) & 1u)) >> 16;
    return (unsigned short)r;
}
__device__ __forceinline__ void acc_bf8s(const uint4 v, const float ns, float* acc) {
    acc[0] += __uint_as_float(v.x << 16) * ns;
    acc[1] += __uint_as_float(v.x & 0xffff0000u) * ns;
    acc[2] += __uint_as_float(v.y << 16) * ns;
    acc[3] += __uint_as_float(v.y & 0xffff0000u) * ns;
    acc[4] += __uint_as_float(v.z << 16) * ns;
    acc[5] += __uint_as_float(v.z & 0xffff0000u) * ns;
    acc[6] += __uint_as_float(v.w << 16) * ns;
    acc[7] += __uint_as_float(v.w & 0xffff0000u) * ns;
}

// ---------------- setup: cursors + head constant + V = W2 @ Wp ----------------
__global__ void setup_kernel(int* __restrict__ gCur, int* __restrict__ gRegCur,
                             int* __restrict__ gRegCurS,
                             const float* __restrict__ W2, const float* __restrict__ Wp,
                             const float* __restrict__ b2, const float* __restrict__ bp,
                             float* __restrict__ consts, float2* __restrict__ V) {
    const int g = blockIdx.x;
    const int tid = threadIdx.x;
    if (g < 13) {                         // 13*256 = 3328 >= NBUCK
        const int b = g * 256 + tid;
        if (b < NBUCK) gCur[b * GSTRIDE] = b * BCAPG;
        return;
    }
    if (g == 14) {                        // region cursors (both streams)
        if (tid < NREG) gRegCur[tid * GSTRIDE] = tid * RCAP;
        else if (tid >= 64 && tid < 64 + NREG) {
            const int r = tid - 64;
            gRegCurS[r * GSTRIDE] = r * RCAP;
        }
        return;
    }
    // block 13: head fold weights + constant
    if (tid < 128) {                      // V[i] = (W2[i]·Wp_a, W2[i]·Wp_c)
        float sa = 0.f, sc = 0.f;
        #pragma unroll 8
        for (int j = 0; j < F; ++j) {
            const float w = W2[tid * F + j];
            sa += w * Wp[j];
            sc += w * Wp[F + j];
        }
        V[tid] = make_float2(sa, sc);
    } else if (tid < 192) {               // wave 2: cc = b2.Wp_a + b2.Wp_c + bp
        const int l = tid - 128;
        const float2 bb = *(const float2*)&b2[2 * l];
        const float2 wa = *(const float2*)&Wp[2 * l];
        const float2 wc = *(const float2*)&Wp[F + 2 * l];
        float s = bb.x * (wa.x + wc.x) + bb.y * (wa.y + wc.y);
        #pragma unroll
        for (int m = 32; m > 0; m >>= 1) s += __shfl_xor(s, m);
        if (l == 0) consts[0] = s + bp[0];
    }
}

// ---------------- fused gemm1 (MFMA) + dual-stream binning (LDS-staged edges) ----------
// 1536 blocks, 6/CU fully resident (26.2 KB smem x 6 = 157 KB <= 160).
// blockIdx%2==1 -> fill role (768 blocks, 2084-edge chunk):
//   ONE global pass: load src/dst, stage {s:u32, d&0x7FF:u16, d>>11:u8} in LDS and
//   build both histograms. Both place phases then read LDS only (~120cy vs 200-900cy
//   global) — cuts the fill role's dependent global-latency chains 3x.
//   ZERO per-edge global atomics.
// blockIdx%2==0 -> gemm role (768 blocks): hs_bf = bf16(x @ W1), 32x128 MFMA tiles.
__global__ __launch_bounds__(256, 6)
void gemm1_fill_kernel(const float* __restrict__ in, const float* __restrict__ W,
                       unsigned short* __restrict__ out_bf,
                       const int* __restrict__ src, const int* __restrict__ dst,
                       int* __restrict__ gRegCur, int* __restrict__ gRegCurS,
                       int* __restrict__ gRegion, unsigned short* __restrict__ gRegionS) {
    __shared__ __align__(16) char smem[26184];

    const int g = blockIdx.x;
    const int tid = threadIdx.x;

    if (g & 1) {                                    // ---- fill role (768 blocks)
        unsigned int*   sA   = (unsigned int*)smem;             // CHUNK u32 (8336)
        unsigned short* d16  = (unsigned short*)(smem + 8336);  // CHUNK u16 (4168)
        unsigned char*  d8   = (unsigned char*)(smem + 12504);  // CHUNK u8  (2084)
        int*            outB = (int*)(smem + 14588);            // CHUNK ints (8336)
        unsigned char*  oReg = (unsigned char*)(smem + 22924);  // CHUNK u8  (2084)
        int* cntD  = (int*)(smem + 25008);                      // 6 x 49 ints
        int* curD  = cntD + NREG;
        int* baseD = curD + NREG;
        int* cntS  = baseD + NREG;
        int* curS  = cntS + NREG;
        int* baseS = curS + NREG;

        const int e0 = (g >> 1) * CHUNK;
        const int nCh = min(CHUNK, NE - e0);

        // ---- single global pass: stage + dual histogram
        if (tid < NREG) { cntD[tid] = 0; cntS[tid] = 0; }
        __syncthreads();
        for (int i = tid; i < nCh; i += 256) {
            const int s = src[e0 + i];
            const int d = dst[e0 + i];
            sA[i]  = (unsigned int)s;
            d16[i] = (unsigned short)(d & 0x7FF);
            d8[i]  = (unsigned char)(d >> 11);
            atomicAdd(&cntD[d >> 11], 1);
            atomicAdd(&cntS[s >> 11], 1);
        }
        __syncthreads();
        if (tid < NREG && cntD[tid] > 0)
            baseD[tid] = atomicAdd(&gRegCur[tid * GSTRIDE], cntD[tid]);
        if (tid >= 64 && tid < 64 + NREG) {
            const int r = tid - 64;
            if (cntS[r] > 0)
                baseS[r] = atomicAdd(&gRegCurS[r * GSTRIDE], cntS[r]);
        }
        if (tid == 0) {
            int run = 0;
            for (int r = 0; r < NREG; ++r) { curD[r] = run; run += cntD[r]; }
        }
        if (tid == 64) {                    // different wave: runs in parallel
            int run = 0;
            for (int r = 0; r < NREG; ++r) { curS[r] = run; run += cntS[r]; }
        }
        __syncthreads();

        // ---- stream 1 (dst key): LDS place + coalesced copy-out
        for (int i = tid; i < nCh; i += 256) {
            const int r = d8[i];
            const int p = atomicAdd(&curD[r], 1);
            outB[p] = (int)(sA[i] | ((unsigned int)d16[i] << 17));
            oReg[p] = (unsigned char)r;
        }
        __syncthreads();
        for (int i = tid; i < nCh; i += 256) {
            const int r = oReg[i];
            const int dstAbs = baseD[r] + (i - (curD[r] - cntD[r]));
            if (dstAbs < (r + 1) * RCAP)
                gRegion[dstAbs] = outB[i];
        }
        __syncthreads();

        // ---- stream 2 (src key): LDS place + coalesced copy-out (u16)
        for (int i = tid; i < nCh; i += 256) {
            const unsigned int s = sA[i];
            const int r = (int)(s >> 11);
            const int p = atomicAdd(&curS[r], 1);
            outB[p] = (int)(s & 0x7FF);
            oReg[p] = (unsigned char)r;
        }
        __syncthreads();
        for (int i = tid; i < nCh; i += 256) {
            const int r = oReg[i];
            const int dstAbs = baseS[r] + (i - (curS[r] - cntS[r]));
            if (dstAbs < (r + 1) * RCAP)
                gRegionS[dstAbs] = (unsigned short)outB[i];
        }
        return;
    }

    // ---- gemm role (768 blocks), tile = 32 rows x 128 cols, ~4 tiles each
    char* A_s = smem;                   // 8 KB fragment-ordered A tile (bf16)

    const int gid  = g >> 1;
    const int w    = tid >> 6;          // wave 0..3 -> cols 32w..32w+31
    const int lane = tid & 63;
    const int ml   = lane & 15;
    const int quad = lane >> 4;

    // preload B frags once: Bf[kb][nb], j: bf16(W[(kb*32+quad*8+j)*F + 32w+nb*16+ml])
    bf16x8 Bf[4][2];
    #pragma unroll
    for (int kb = 0; kb < 4; ++kb) {
        #pragma unroll
        for (int nb = 0; nb < 2; ++nb) {
            const int n = 32 * w + nb * 16 + ml;
            const int k0 = kb * 32 + quad * 8;
            #pragma unroll
            for (int j = 0; j < 8; ++j)
                Bf[kb][nb][j] = (short)f2bf(W[(k0 + j) * F + n]);
        }
    }

    const int nTiles = NN / 32;                     // 3125
    for (int tile = gid; tile < nTiles; tile += NGEMM) {
        const int row0 = tile * 32;
        __syncthreads();
        // stage A tile in fragment order: 512 chunks of 8 floats -> bf16
        #pragma unroll
        for (int c = 0; c < 2; ++c) {
            const int i2 = tid + 256 * c;           // 0..511
            const int m  = i2 >> 4;                 // row 0..31
            const int o  = i2 & 15;                 // k-octet
            const float* xr = &in[(size_t)(row0 + m) * F + o * 8];
            const float4 v0 = *(const float4*)xr;
            const float4 v1 = *(const float4*)(xr + 4);
            short h8[8];
            h8[0] = (short)f2bf(v0.x); h8[1] = (short)f2bf(v0.y);
            h8[2] = (short)f2bf(v0.z); h8[3] = (short)f2bf(v0.w);
            h8[4] = (short)f2bf(v1.x); h8[5] = (short)f2bf(v1.y);
            h8[6] = (short)f2bf(v1.z); h8[7] = (short)f2bf(v1.w);
            const int kb2 = o >> 2, q2 = o & 3, ml2 = m & 15, mh2 = m >> 4;
            const int fo = (((mh2 * 4 + kb2) * 64) + q2 * 16 + ml2) * 16;
            *(bf16x8*)(A_s + fo) = *(bf16x8*)h8;
        }
        __syncthreads();

        f32x4 acc00 = {0,0,0,0}, acc01 = {0,0,0,0}, acc10 = {0,0,0,0}, acc11 = {0,0,0,0};
        #pragma unroll
        for (int kb = 0; kb < 4; ++kb) {
            const bf16x8 ah0 = *(const bf16x8*)(A_s + (kb * 64 + lane) * 16);
            const bf16x8 ah1 = *(const bf16x8*)(A_s + ((4 + kb) * 64 + lane) * 16);
            acc00 = __builtin_amdgcn_mfma_f32_16x16x32_bf16(ah0, Bf[kb][0], acc00, 0, 0, 0);
            acc01 = __builtin_amdgcn_mfma_f32_16x16x32_bf16(ah0, Bf[kb][1], acc01, 0, 0, 0);
            acc10 = __builtin_amdgcn_mfma_f32_16x16x32_bf16(ah1, Bf[kb][0], acc10, 0, 0, 0);
            acc11 = __builtin_amdgcn_mfma_f32_16x16x32_bf16(ah1, Bf[kb][1], acc11, 0, 0, 0);
        }

        // epilogue: C/D layout col=lane&15, row=quad*4+reg
        #pragma unroll
        for (int mh = 0; mh < 2; ++mh) {
            #pragma unroll
            for (int nb = 0; nb < 2; ++nb) {
                const f32x4 a = (mh == 0) ? (nb == 0 ? acc00 : acc01)
                                          : (nb == 0 ? acc10 : acc11);
                const int row = row0 + mh * 16 + quad * 4;
                const int col = 32 * w + nb * 16 + ml;
                #pragma unroll
                for (int r = 0; r < 4; ++r)
                    out_bf[(size_t)(row + r) * F + col] = f2bf(a[r]);
            }
        }
    }
}

// ---------------- pass 2: region -> fine buckets; + per-region deg histogram ----------------
__global__ __launch_bounds__(256)
void pass2_kernel(const int* __restrict__ gRegion, const unsigned short* __restrict__ gRegionS,
                  const int* __restrict__ gRegCur, const int* __restrict__ gRegCurS,
                  int* __restrict__ gCur, int* __restrict__ srcPart,
                  float* __restrict__ norm_src) {
    __shared__ __align__(16) char smem[12544];

    const int r   = blockIdx.x / P2J;
    const int j   = blockIdx.x % P2J;
    const int tid = threadIdx.x;

    if (j == P2SPLIT) {                       // ---- deg role: src histogram
        int* hist = (int*)smem;               // 2048 ints
        const int total = min(gRegCurS[r * GSTRIDE] - r * RCAP, RCAP);
        for (int t = tid; t < 2048; t += 256) hist[t] = 0;
        __syncthreads();
        for (int i = tid; i < total; i += 256)
            atomicAdd(&hist[gRegionS[r * RCAP + i]], 1);
        __syncthreads();
        const int nlo = r * 2048;
        for (int t = tid; t < 2048; t += 256) {
            const int n = nlo + t;
            if (n < NN) norm_src[n] = rsqrtf((float)max(hist[t], 1));
        }
        return;
    }

    // ---- sort role
    int* sortedL = (int*)smem;                              // P2MAX ints (9216 B)
    unsigned char* fbOf = (unsigned char*)(smem + 9216);    // P2MAX u8 (2304 B)
    int* cnt  = (int*)(smem + 11520);                       // 64 ints
    int* cur  = cnt + 64;
    int* base = cur + 64;

    const int total = min(gRegCur[r * GSTRIDE] - r * RCAP, RCAP);
    const int per = (total + P2SPLIT - 1) / P2SPLIT;
    const int i0 = j * per;
    const int i1 = min(total, i0 + per);
    const int n = i1 - i0;                       // may be <= 0 for tail blocks

    if (tid < 64) cnt[tid] = 0;
    __syncthreads();

    int v[9];                                    // ceil(P2MAX/256) = 9
    #pragma unroll
    for (int k = 0; k < 9; ++k) {
        const int i = tid + k * 256;
        if (i < n) {
            const int vv = gRegion[r * RCAP + i0 + i];
            v[k] = vv;
            atomicAdd(&cnt[vv >> 22], 1);        // fb = (d&0x7FF)>>5
        }
    }
    __syncthreads();
    if (tid < 64 && cnt[tid] > 0)
        base[tid] = atomicAdd(&gCur[(r * 64 + tid) * GSTRIDE], cnt[tid]);
    if (tid == 0) {
        int run = 0;
        for (int f = 0; f < 64; ++f) { cur[f] = run; run += cnt[f]; }
    }
    __syncthreads();
    #pragma unroll
    for (int k = 0; k < 9; ++k) {
        const int i = tid + k * 256;
        if (i < n) {
            const int fb = v[k] >> 22;
            const int p = atomicAdd(&cur[fb], 1);
            sortedL[p] = v[k] & 0x3FFFFF;        // s | ((d&31)<<17)
            fbOf[p] = (unsigned char)fb;
        }
    }
    __syncthreads();
    for (int i = tid; i < n; i += 256) {
        const int fb = fbOf[i];
        const int dstAbs = base[fb] + (i - (cur[fb] - cnt[fb]));
        if (dstAbs < (r * 64 + fb + 1) * BCAPG)
            srcPart[dstAbs] = sortedL[i];
    }
}

// ---------------- gather + per-bucket LDS counting sort + fused layer-2 head fold ----------------
__global__ __launch_bounds__(256)
void gather_sort_kernel(const unsigned short* __restrict__ hs,
                        int* __restrict__ srcPart, const int* __restrict__ gCur,
                        const float* __restrict__ norm_src, const float* __restrict__ bias,
                        const float2* __restrict__ V, float2* __restrict__ uw,
                        int* __restrict__ offs, int* __restrict__ ends,
                        float* __restrict__ norm_dst) {
    __shared__ int cnt[32];
    __shared__ int loc[32];       // inclusive prefix
    __shared__ int cur[32];
    __shared__ int nextNode;
    __shared__ int sortedL[BCAPG];

    const int b   = blockIdx.x;
    const int tid = threadIdx.x;
    const int nlo = b * 32;                      // NN == NBUCK*32 exactly
    const int eBase = b * BCAPG;
    const int total = min(gCur[b * GSTRIDE] - eBase, BCAPG);

    if (tid < 32) cnt[tid] = 0;
    if (tid == 0) nextNode = 0;
    __syncthreads();
    for (int i = tid; i < total; i += 256)
        atomicAdd(&cnt[(srcPart[eBase + i] >> 17) & 31], 1);
    __syncthreads();
    if (tid < 64) {                              // wave-0 register prefix scan
        const int l32 = tid & 31;
        const int c = cnt[l32];
        int v = c;
        #pragma unroll
        for (int off = 1; off < 32; off <<= 1) {
            const int t = __shfl_up(v, off, 32);
            if (l32 >= off) v += t;
        }
        if (tid < 32) {
            loc[tid] = v;                        // inclusive prefix
            cur[tid] = v - c;
            const int st = eBase + v - c;
            offs[nlo + tid] = st;
            ends[nlo + tid] = st + c;
            norm_dst[nlo + tid] = rsqrtf((float)max(c, 1));
        }
    }
    __syncthreads();
    for (int i = tid; i < total; i += 256) {
        const int v = srcPart[eBase + i];
        const int r = atomicAdd(&cur[(v >> 17) & 31], 1);
        sortedL[r] = v & 0x1FFFF;
    }
    __syncthreads();
    // coalesced write of sorted src ids (for ac_kernel)
    for (int i = tid; i < total; i += 256)
        srcPart[eBase + i] = sortedL[i];
    __syncthreads();

    // ---- feature gather (dynamic: waves pull nodes; 16 lanes/edge, 8 bf16 cols/lane)
    const int l  = tid & 63;
    const int q  = l >> 4;
    const int c8 = (l & 15) * 8;
    float bb[8];
    *(float4*)&bb[0] = *(const float4*)&bias[c8];
    *(float4*)&bb[4] = *(const float4*)&bias[c8 + 4];
    float2 Vl[8];
    #pragma unroll
    for (int k = 0; k < 8; ++k) Vl[k] = V[c8 + k];

    for (;;) {
        int nh;
        if (l == 0) nh = atomicAdd(&nextNode, 1);
        nh = __shfl(nh, 0);
        if (nh >= 32) break;

        const int end = loc[nh];
        const int beg = end - cnt[nh];
        float acc[8] = {0.f, 0.f, 0.f, 0.f, 0.f, 0.f, 0.f, 0.f};
        int j = beg;
        for (; j + 16 <= end; j += 16) {      // 16 edges in flight per wave
            const int s0 = sortedL[j + q];
            const int s1 = sortedL[j + 4 + q];
            const int s2 = sortedL[j + 8 + q];
            const int s3 = sortedL[j + 12 + q];
            const float ns0 = norm_src[s0];
            const float ns1 = norm_src[s1];
            const float ns2 = norm_src[s2];
            const float ns3 = norm_src[s3];
            const uint4 v0 = *(const uint4*)&hs[(size_t)s0 * F + c8];
            const uint4 v1 = *(const uint4*)&hs[(size_t)s1 * F + c8];
            const uint4 v2 = *(const uint4*)&hs[(size_t)s2 * F + c8];
            const uint4 v3 = *(const uint4*)&hs[(size_t)s3 * F + c8];
            acc_bf8s(v0, ns0, acc);
            acc_bf8s(v1, ns1, acc);
            acc_bf8s(v2, ns2, acc);
            acc_bf8s(v3, ns3, acc);
        }
        for (; j + 8 <= end; j += 8) {
            const int s0 = sortedL[j + q];
            const int s1 = sortedL[j + 4 + q];
            const float ns0 = norm_src[s0];
            const float ns1 = norm_src[s1];
            const uint4 v0 = *(const uint4*)&hs[(size_t)s0 * F + c8];
            const uint4 v1 = *(const uint4*)&hs[(size_t)s1 * F + c8];
            acc_bf8s(v0, ns0, acc);
            acc_bf8s(v1, ns1, acc);
        }
        for (; j + 4 <= end; j += 4) {
            const int s = sortedL[j + q];
            const float ns = norm_src[s];
            const uint4 v = *(const uint4*)&hs[(size_t)s * F + c8];
            acc_bf8s(v, ns, acc);
        }
        if (j + q < end) {
            const int s = sortedL[j + q];
            const float ns = norm_src[s];
            const uint4 v = *(const uint4*)&hs[(size_t)s * F + c8];
            acc_bf8s(v, ns, acc);
        }
        #pragma unroll
        for (int k = 0; k < 8; ++k) {
            acc[k] += __shfl_xor(acc[k], 16);
            acc[k] += __shfl_xor(acc[k], 32);
        }

        const int n = nlo + nh;
        const float nd = rsqrtf((float)max(cnt[nh], 1));
        float pa = 0.f, pc = 0.f;
        #pragma unroll
        for (int k = 0; k < 8; ++k) {
            const float ok = fmaxf(acc[k] * nd + bb[k], 0.f);
            pa += ok * Vl[k].x;
            pc += ok * Vl[k].y;
        }
        #pragma unroll
        for (int m = 1; m <= 8; m <<= 1) {
            pa += __shfl_xor(pa, m);
            pc += __shfl_xor(pc, m);
        }
        if (l == 0) {
            const float ns = norm_src[n];
            uw[n] = make_float2(ns * pa, ns * pc);
        }
    }
}

// ---------------- layer-2 aggregation: bucket-parallel (8 threads/node) ----------------
__global__ __launch_bounds__(256, 8)
void ac_kernel(const float2* __restrict__ uw, const int* __restrict__ sorted_src,
               const int* __restrict__ offs, const int* __restrict__ ends,
               const float* __restrict__ norm_dst,
               float* __restrict__ A, float* __restrict__ C) {
    const int tid = threadIdx.x;
    const int n   = blockIdx.x * 32 + (tid >> 3);   // NN == NBUCK*32 exactly
    const int sub = tid & 7;
    const int beg = offs[n];
    const int end = ends[n];
    float sx = 0.f, sy = 0.f;
    for (int j = beg + sub; j < end; j += 8) {
        const float2 t = uw[sorted_src[j]];
        sx += t.x;
        sy += t.y;
    }
    sx += __shfl_xor(sx, 1); sy += __shfl_xor(sy, 1);
    sx += __shfl_xor(sx, 2); sy += __shfl_xor(sy, 2);
    sx += __shfl_xor(sx, 4); sy += __shfl_xor(sy, 4);
    if (sub == 0) {
        const float nd = norm_dst[n];
        A[n] = nd * sx;
        C[n] = nd * sy;
    }
}

// ---------------- edge scores (4-wide) ----------------
__global__ void score_kernel(const float* __restrict__ A, const float* __restrict__ C,
                             const int4* __restrict__ src4, const int4* __restrict__ dst4,
                             const float* __restrict__ consts, float4* __restrict__ out4,
                             int nE4) {
    const int i = blockIdx.x * blockDim.x + threadIdx.x;
    if (i < nE4) {
        const int4 s = src4[i];
        const int4 d = dst4[i];
        const float cc = consts[0];
        float4 o;
        o.x = 1.f / (1.f + __expf(-(A[s.x] + C[d.x] + cc)));
        o.y = 1.f / (1.f + __expf(-(A[s.y] + C[d.y] + cc)));
        o.z = 1.f / (1.f + __expf(-(A[s.z] + C[d.z] + cc)));
        o.w = 1.f / (1.f + __expf(-(A[s.w] + C[d.w] + cc)));
        out4[i] = o;
    }
}

extern "C" void kernel_launch(void* const* d_in, const int* in_sizes, int n_in,
                              void* d_out, int out_size, void* d_ws, size_t ws_size,
                              hipStream_t stream) {
    const float* x  = (const float*)d_in[0];
    const float* W1 = (const float*)d_in[1];
    const float* b1 = (const float*)d_in[2];
    const float* W2 = (const float*)d_in[3];
    const float* b2 = (const float*)d_in[4];
    const float* Wp = (const float*)d_in[5];
    const float* bp = (const float*)d_in[6];
    const int*   src = (const int*)d_in[7];
    const int*   dst = (const int*)d_in[8];
    float* out = (float*)d_out;

    float* ws        = (float*)d_ws;
    float* norm_src  = ws;                        // NPAD
    float* bufA      = ws + NPAD;                 // NPAD: A[]
    float* bufC      = ws + 2 * NPAD;             // NPAD: C[]
    float* norm_dst  = ws + 3 * NPAD;             // NPAD
    int*   offs      = (int*)(ws + 4 * NPAD);     // NPAD
    int*   ends      = offs + NPAD;               // NPAD
    int*   gCur      = ends + NPAD;               // NBUCK*GSTRIDE = 50000, pad 50176
    int*   gRegCur   = gCur + 50176;              // NREG*GSTRIDE = 784, pad 1024
    int*   gRegCurS  = gRegCur + 1024;            // NREG*GSTRIDE = 784, pad 1024
    float* consts    = (float*)(gRegCurS + 1024); // 16
    float2* V        = (float2*)(consts + 16);    // 128 float2
    float2* uw       = V + 128;                   // NN float2
    int*   srcPart   = (int*)(uw + NN);           // NBUCK*BCAPG ints (9.6 MB)
    unsigned short* hs_bf = (unsigned short*)(srcPart + (size_t)NBUCK * BCAPG);  // NN*F bf16
    int*   gRegion   = (int*)(hs_bf + (size_t)NN * F);          // NREG*RCAP ints (7.2 MB)
    unsigned short* gRegionS = (unsigned short*)(gRegion + (size_t)NREG * RCAP); // NREG*RCAP u16 (3.6 MB)

    // cursors + folded head weights
    setup_kernel<<<15, 256, 0, stream>>>(gCur, gRegCur, gRegCurS, W2, Wp, b2, bp, consts, V);

    // layer-1 MFMA GEMM overlapped with dual-stream coarse binning (LDS-staged edges)
    gemm1_fill_kernel<<<NFILL + NGEMM, 256, 0, stream>>>(x, W1, hs_bf, src, dst,
                                                         gRegCur, gRegCurS, gRegion, gRegionS);

    // pass 2: regions -> fine 32-node buckets (coalesced) + per-region deg histogram -> norm_src
    pass2_kernel<<<NREG * P2J, 256, 0, stream>>>(gRegion, gRegionS, gRegCur, gRegCurS,
                                                 gCur, srcPart, norm_src);

    // per-bucket LDS sort + feature gather + folded layer-2 head
    gather_sort_kernel<<<NBUCK, 256, 0, stream>>>(hs_bf, srcPart, gCur, norm_src, b1,
                                                  V, uw, offs, ends, norm_dst);

    // layer-2 aggregation: bucket-parallel, 8 threads per node
    ac_kernel<<<NBUCK, 256, 0, stream>>>(uw, srcPart, offs, ends, norm_dst,
                                         bufA, bufC);

    // edge scores (NE divisible by 4)
    score_kernel<<<(NE / 4 + 255) / 256, 256, 0, stream>>>(bufA, bufC, (const int4*)src,
                                                           (const int4*)dst, consts,
                                                           (float4*)out, NE / 4);
}

// Round 14
// 278.651 us; speedup vs baseline: 1.0298x; 1.0298x over previous
//
#include <hip/hip_runtime.h>
#include <cstdint>
#include <cstddef>

#define NN 100000
#define NE 1600000
#define F  128
#define NPAD 100352          // 98 * 1024
#define NBUCK 3125           // NN / 32 fine buckets of 32 nodes (gather granularity)
#define BCAPG 768            // fine bucket capacity (mean 512, +11 sd)
#define NFILL 768            // fill-role blocks
#define CHUNK 2084           // ceil(NE / NFILL)
#define NGEMM 768            // gemm-role blocks (grid 1536, 6/CU resident)
#define GSTRIDE 16           // cursor padding: one counter per 64B line
#define NREG 49              // coarse regions (2048 nodes each)
#define RCAP 36864           // region capacity (mean ~32650, +23 sd)
#define P2SPLIT 16           // pass-2 sort blocks per region
#define P2J 17               // + 1 deg-histogram block per region
#define P2MAX 2304           // ceil(RCAP / P2SPLIT)

typedef __attribute__((ext_vector_type(8))) short bf16x8;
typedef __attribute__((ext_vector_type(4))) float f32x4;

// bf16 helpers (RNE)
__device__ __forceinline__ unsigned short f2bf(float f) {
    unsigned u = __float_as_uint(f);
    unsigned r = (u + 0x7fffu + ((u >> 16) & 1u)) >> 16;
    return (unsigned short)r;
}
__device__ __forceinline__ void acc_bf8s(const uint4 v, const float ns, float* acc) {
    acc[0] += __uint_as_float(v.x << 16) * ns;
    acc[1] += __uint_as_float(v.x & 0xffff0000u) * ns;
    acc[2] += __uint_as_float(v.y << 16) * ns;
    acc[3] += __uint_as_float(v.y & 0xffff0000u) * ns;
    acc[4] += __uint_as_float(v.z << 16) * ns;
    acc[5] += __uint_as_float(v.z & 0xffff0000u) * ns;
    acc[6] += __uint_as_float(v.w << 16) * ns;
    acc[7] += __uint_as_float(v.w & 0xffff0000u) * ns;
}

// ---------------- setup: cursors + head constant + V = W2 @ Wp ----------------
__global__ void setup_kernel(int* __restrict__ gCur, int* __restrict__ gRegCur,
                             int* __restrict__ gRegCurS,
                             const float* __restrict__ W2, const float* __restrict__ Wp,
                             const float* __restrict__ b2, const float* __restrict__ bp,
                             float* __restrict__ consts, float2* __restrict__ V) {
    const int g = blockIdx.x;
    const int tid = threadIdx.x;
    if (g < 13) {                         // 13*256 = 3328 >= NBUCK
        const int b = g * 256 + tid;
        if (b < NBUCK) gCur[b * GSTRIDE] = b * BCAPG;
        return;
    }
    if (g == 14) {                        // region cursors (both streams)
        if (tid < NREG) gRegCur[tid * GSTRIDE] = tid * RCAP;
        else if (tid >= 64 && tid < 64 + NREG) {
            const int r = tid - 64;
            gRegCurS[r * GSTRIDE] = r * RCAP;
        }
        return;
    }
    // block 13: head fold weights + constant
    if (tid < 128) {                      // V[i] = (W2[i]·Wp_a, W2[i]·Wp_c)
        float sa = 0.f, sc = 0.f;
        #pragma unroll 8
        for (int j = 0; j < F; ++j) {
            const float w = W2[tid * F + j];
            sa += w * Wp[j];
            sc += w * Wp[F + j];
        }
        V[tid] = make_float2(sa, sc);
    } else if (tid < 192) {               // wave 2: cc = b2.Wp_a + b2.Wp_c + bp
        const int l = tid - 128;
        const float2 bb = *(const float2*)&b2[2 * l];
        const float2 wa = *(const float2*)&Wp[2 * l];
        const float2 wc = *(const float2*)&Wp[F + 2 * l];
        float s = bb.x * (wa.x + wc.x) + bb.y * (wa.y + wc.y);
        #pragma unroll
        for (int m = 32; m > 0; m >>= 1) s += __shfl_xor(s, m);
        if (l == 0) consts[0] = s + bp[0];
    }
}

// ---------------- fused gemm1 (MFMA) + dual-stream coarse binning (fused hist) ----------
// 1536 blocks, 6/CU fully resident. [round-12 verified best: 278.1 us]
// blockIdx%2==1 -> fill role (768 blocks, 2084-edge chunk):
//   ONE histogram pass computes both dst>>11 and src>>11 counts; both claims issue
//   from different waves; then place+copy-out per stream (staging buffer reused).
//   ZERO per-edge global atomics. smem 11.6 KB -> 6/CU fits.
//   (r13 lesson: LDS-staging the edges regressed — 2nd/3rd passes are L2-hot;
//    tripling smem worsened the cold ramp with zero steady-state win.)
// blockIdx%2==0 -> gemm role (768 blocks): hs_bf = bf16(x @ W1), 32x128 MFMA tiles.
__global__ __launch_bounds__(256, 6)
void gemm1_fill_kernel(const float* __restrict__ in, const float* __restrict__ W,
                       unsigned short* __restrict__ out_bf,
                       const int* __restrict__ src, const int* __restrict__ dst,
                       int* __restrict__ gRegCur, int* __restrict__ gRegCurS,
                       int* __restrict__ gRegion, unsigned short* __restrict__ gRegionS) {
    __shared__ __align__(16) char smem[11616];

    const int g = blockIdx.x;
    const int tid = threadIdx.x;

    if (g & 1) {                                    // ---- fill role (768 blocks)
        int* sortedL = (int*)smem;                          // CHUNK ints (8336 B)
        unsigned char* regOf = (unsigned char*)(sortedL + CHUNK);  // CHUNK u8
        int* cntD  = (int*)(smem + 10424);                  // 6 x 49 ints
        int* curD  = cntD + NREG;
        int* baseD = curD + NREG;
        int* cntS  = baseD + NREG;
        int* curS  = cntS + NREG;
        int* baseS = curS + NREG;

        const int e0 = (g >> 1) * CHUNK;
        const int nCh = min(CHUNK, NE - e0);

        // ---- fused histogram pass (both keys)
        if (tid < NREG) { cntD[tid] = 0; cntS[tid] = 0; }
        __syncthreads();
        for (int i = tid; i < nCh; i += 256) {
            const int s = src[e0 + i];
            const int d = dst[e0 + i];
            atomicAdd(&cntD[d >> 11], 1);
            atomicAdd(&cntS[s >> 11], 1);
        }
        __syncthreads();
        if (tid < NREG && cntD[tid] > 0)
            baseD[tid] = atomicAdd(&gRegCur[tid * GSTRIDE], cntD[tid]);
        if (tid >= 64 && tid < 64 + NREG) {
            const int r = tid - 64;
            if (cntS[r] > 0)
                baseS[r] = atomicAdd(&gRegCurS[r * GSTRIDE], cntS[r]);
        }
        if (tid == 0) {
            int run = 0;
            for (int r = 0; r < NREG; ++r) { curD[r] = run; run += cntD[r]; }
        }
        if (tid == 64) {                    // different wave: runs in parallel
            int run = 0;
            for (int r = 0; r < NREG; ++r) { curS[r] = run; run += cntS[r]; }
        }
        __syncthreads();

        // ---- stream 1 (dst key): place + coalesced copy-out
        for (int i = tid; i < nCh; i += 256) {
            const int s = src[e0 + i];
            const int d = dst[e0 + i];
            const int r = d >> 11;
            const int p = atomicAdd(&curD[r], 1);
            sortedL[p] = s | ((d & 0x7FF) << 17);
            regOf[p] = (unsigned char)r;
        }
        __syncthreads();
        for (int i = tid; i < nCh; i += 256) {
            const int r = regOf[i];
            const int dstAbs = baseD[r] + (i - (curD[r] - cntD[r]));
            if (dstAbs < (r + 1) * RCAP)
                gRegion[dstAbs] = sortedL[i];
        }
        __syncthreads();

        // ---- stream 2 (src key): place + coalesced copy-out (u16)
        for (int i = tid; i < nCh; i += 256) {
            const int s = src[e0 + i];
            const int r = s >> 11;
            const int p = atomicAdd(&curS[r], 1);
            sortedL[p] = s;
            regOf[p] = (unsigned char)r;
        }
        __syncthreads();
        for (int i = tid; i < nCh; i += 256) {
            const int r = regOf[i];
            const int dstAbs = baseS[r] + (i - (curS[r] - cntS[r]));
            if (dstAbs < (r + 1) * RCAP)
                gRegionS[dstAbs] = (unsigned short)(sortedL[i] & 0x7FF);
        }
        return;
    }

    // ---- gemm role (768 blocks), tile = 32 rows x 128 cols, ~4 tiles each
    char* A_s = smem;                   // 8 KB fragment-ordered A tile (bf16)

    const int gid  = g >> 1;
    const int w    = tid >> 6;          // wave 0..3 -> cols 32w..32w+31
    const int lane = tid & 63;
    const int ml   = lane & 15;
    const int quad = lane >> 4;

    // preload B frags once: Bf[kb][nb], j: bf16(W[(kb*32+quad*8+j)*F + 32w+nb*16+ml])
    bf16x8 Bf[4][2];
    #pragma unroll
    for (int kb = 0; kb < 4; ++kb) {
        #pragma unroll
        for (int nb = 0; nb < 2; ++nb) {
            const int n = 32 * w + nb * 16 + ml;
            const int k0 = kb * 32 + quad * 8;
            #pragma unroll
            for (int j = 0; j < 8; ++j)
                Bf[kb][nb][j] = (short)f2bf(W[(k0 + j) * F + n]);
        }
    }

    const int nTiles = NN / 32;                     // 3125
    for (int tile = gid; tile < nTiles; tile += NGEMM) {
        const int row0 = tile * 32;
        __syncthreads();
        // stage A tile in fragment order: 512 chunks of 8 floats -> bf16
        #pragma unroll
        for (int c = 0; c < 2; ++c) {
            const int i2 = tid + 256 * c;           // 0..511
            const int m  = i2 >> 4;                 // row 0..31
            const int o  = i2 & 15;                 // k-octet
            const float* xr = &in[(size_t)(row0 + m) * F + o * 8];
            const float4 v0 = *(const float4*)xr;
            const float4 v1 = *(const float4*)(xr + 4);
            short h8[8];
            h8[0] = (short)f2bf(v0.x); h8[1] = (short)f2bf(v0.y);
            h8[2] = (short)f2bf(v0.z); h8[3] = (short)f2bf(v0.w);
            h8[4] = (short)f2bf(v1.x); h8[5] = (short)f2bf(v1.y);
            h8[6] = (short)f2bf(v1.z); h8[7] = (short)f2bf(v1.w);
            const int kb2 = o >> 2, q2 = o & 3, ml2 = m & 15, mh2 = m >> 4;
            const int fo = (((mh2 * 4 + kb2) * 64) + q2 * 16 + ml2) * 16;
            *(bf16x8*)(A_s + fo) = *(bf16x8*)h8;
        }
        __syncthreads();

        f32x4 acc00 = {0,0,0,0}, acc01 = {0,0,0,0}, acc10 = {0,0,0,0}, acc11 = {0,0,0,0};
        #pragma unroll
        for (int kb = 0; kb < 4; ++kb) {
            const bf16x8 ah0 = *(const bf16x8*)(A_s + (kb * 64 + lane) * 16);
            const bf16x8 ah1 = *(const bf16x8*)(A_s + ((4 + kb) * 64 + lane) * 16);
            acc00 = __builtin_amdgcn_mfma_f32_16x16x32_bf16(ah0, Bf[kb][0], acc00, 0, 0, 0);
            acc01 = __builtin_amdgcn_mfma_f32_16x16x32_bf16(ah0, Bf[kb][1], acc01, 0, 0, 0);
            acc10 = __builtin_amdgcn_mfma_f32_16x16x32_bf16(ah1, Bf[kb][0], acc10, 0, 0, 0);
            acc11 = __builtin_amdgcn_mfma_f32_16x16x32_bf16(ah1, Bf[kb][1], acc11, 0, 0, 0);
        }

        // epilogue: C/D layout col=lane&15, row=quad*4+reg
        #pragma unroll
        for (int mh = 0; mh < 2; ++mh) {
            #pragma unroll
            for (int nb = 0; nb < 2; ++nb) {
                const f32x4 a = (mh == 0) ? (nb == 0 ? acc00 : acc01)
                                          : (nb == 0 ? acc10 : acc11);
                const int row = row0 + mh * 16 + quad * 4;
                const int col = 32 * w + nb * 16 + ml;
                #pragma unroll
                for (int r = 0; r < 4; ++r)
                    out_bf[(size_t)(row + r) * F + col] = f2bf(a[r]);
            }
        }
    }
}

// ---------------- pass 2: region -> fine buckets; + per-region deg histogram ----------------
__global__ __launch_bounds__(256)
void pass2_kernel(const int* __restrict__ gRegion, const unsigned short* __restrict__ gRegionS,
                  const int* __restrict__ gRegCur, const int* __restrict__ gRegCurS,
                  int* __restrict__ gCur, int* __restrict__ srcPart,
                  float* __restrict__ norm_src) {
    __shared__ __align__(16) char smem[12544];

    const int r   = blockIdx.x / P2J;
    const int j   = blockIdx.x % P2J;
    const int tid = threadIdx.x;

    if (j == P2SPLIT) {                       // ---- deg role: src histogram
        int* hist = (int*)smem;               // 2048 ints
        const int total = min(gRegCurS[r * GSTRIDE] - r * RCAP, RCAP);
        for (int t = tid; t < 2048; t += 256) hist[t] = 0;
        __syncthreads();
        for (int i = tid; i < total; i += 256)
            atomicAdd(&hist[gRegionS[r * RCAP + i]], 1);
        __syncthreads();
        const int nlo = r * 2048;
        for (int t = tid; t < 2048; t += 256) {
            const int n = nlo + t;
            if (n < NN) norm_src[n] = rsqrtf((float)max(hist[t], 1));
        }
        return;
    }

    // ---- sort role
    int* sortedL = (int*)smem;                              // P2MAX ints (9216 B)
    unsigned char* fbOf = (unsigned char*)(smem + 9216);    // P2MAX u8 (2304 B)
    int* cnt  = (int*)(smem + 11520);                       // 64 ints
    int* cur  = cnt + 64;
    int* base = cur + 64;

    const int total = min(gRegCur[r * GSTRIDE] - r * RCAP, RCAP);
    const int per = (total + P2SPLIT - 1) / P2SPLIT;
    const int i0 = j * per;
    const int i1 = min(total, i0 + per);
    const int n = i1 - i0;                       // may be <= 0 for tail blocks

    if (tid < 64) cnt[tid] = 0;
    __syncthreads();

    int v[9];                                    // ceil(P2MAX/256) = 9
    #pragma unroll
    for (int k = 0; k < 9; ++k) {
        const int i = tid + k * 256;
        if (i < n) {
            const int vv = gRegion[r * RCAP + i0 + i];
            v[k] = vv;
            atomicAdd(&cnt[vv >> 22], 1);        // fb = (d&0x7FF)>>5
        }
    }
    __syncthreads();
    if (tid < 64 && cnt[tid] > 0)
        base[tid] = atomicAdd(&gCur[(r * 64 + tid) * GSTRIDE], cnt[tid]);
    if (tid == 0) {
        int run = 0;
        for (int f = 0; f < 64; ++f) { cur[f] = run; run += cnt[f]; }
    }
    __syncthreads();
    #pragma unroll
    for (int k = 0; k < 9; ++k) {
        const int i = tid + k * 256;
        if (i < n) {
            const int fb = v[k] >> 22;
            const int p = atomicAdd(&cur[fb], 1);
            sortedL[p] = v[k] & 0x3FFFFF;        // s | ((d&31)<<17)
            fbOf[p] = (unsigned char)fb;
        }
    }
    __syncthreads();
    for (int i = tid; i < n; i += 256) {
        const int fb = fbOf[i];
        const int dstAbs = base[fb] + (i - (cur[fb] - cnt[fb]));
        if (dstAbs < (r * 64 + fb + 1) * BCAPG)
            srcPart[dstAbs] = sortedL[i];
    }
}

// ---------------- gather + per-bucket LDS counting sort + fused layer-2 head fold ----------------
__global__ __launch_bounds__(256)
void gather_sort_kernel(const unsigned short* __restrict__ hs,
                        int* __restrict__ srcPart, const int* __restrict__ gCur,
                        const float* __restrict__ norm_src, const float* __restrict__ bias,
                        const float2* __restrict__ V, float2* __restrict__ uw,
                        int* __restrict__ offs, int* __restrict__ ends,
                        float* __restrict__ norm_dst) {
    __shared__ int cnt[32];
    __shared__ int loc[32];       // inclusive prefix
    __shared__ int cur[32];
    __shared__ int nextNode;
    __shared__ int sortedL[BCAPG];

    const int b   = blockIdx.x;
    const int tid = threadIdx.x;
    const int nlo = b * 32;                      // NN == NBUCK*32 exactly
    const int eBase = b * BCAPG;
    const int total = min(gCur[b * GSTRIDE] - eBase, BCAPG);

    if (tid < 32) cnt[tid] = 0;
    if (tid == 0) nextNode = 0;
    __syncthreads();
    for (int i = tid; i < total; i += 256)
        atomicAdd(&cnt[(srcPart[eBase + i] >> 17) & 31], 1);
    __syncthreads();
    if (tid < 64) {                              // wave-0 register prefix scan
        const int l32 = tid & 31;
        const int c = cnt[l32];
        int v = c;
        #pragma unroll
        for (int off = 1; off < 32; off <<= 1) {
            const int t = __shfl_up(v, off, 32);
            if (l32 >= off) v += t;
        }
        if (tid < 32) {
            loc[tid] = v;                        // inclusive prefix
            cur[tid] = v - c;
            const int st = eBase + v - c;
            offs[nlo + tid] = st;
            ends[nlo + tid] = st + c;
            norm_dst[nlo + tid] = rsqrtf((float)max(c, 1));
        }
    }
    __syncthreads();
    for (int i = tid; i < total; i += 256) {
        const int v = srcPart[eBase + i];
        const int r = atomicAdd(&cur[(v >> 17) & 31], 1);
        sortedL[r] = v & 0x1FFFF;
    }
    __syncthreads();
    // coalesced write of sorted src ids (for ac_kernel)
    for (int i = tid; i < total; i += 256)
        srcPart[eBase + i] = sortedL[i];
    __syncthreads();

    // ---- feature gather (dynamic: waves pull nodes; 16 lanes/edge, 8 bf16 cols/lane)
    const int l  = tid & 63;
    const int q  = l >> 4;
    const int c8 = (l & 15) * 8;
    float bb[8];
    *(float4*)&bb[0] = *(const float4*)&bias[c8];
    *(float4*)&bb[4] = *(const float4*)&bias[c8 + 4];
    float2 Vl[8];
    #pragma unroll
    for (int k = 0; k < 8; ++k) Vl[k] = V[c8 + k];

    for (;;) {
        int nh;
        if (l == 0) nh = atomicAdd(&nextNode, 1);
        nh = __shfl(nh, 0);
        if (nh >= 32) break;

        const int end = loc[nh];
        const int beg = end - cnt[nh];
        float acc[8] = {0.f, 0.f, 0.f, 0.f, 0.f, 0.f, 0.f, 0.f};
        int j = beg;
        for (; j + 16 <= end; j += 16) {      // 16 edges in flight per wave
            const int s0 = sortedL[j + q];
            const int s1 = sortedL[j + 4 + q];
            const int s2 = sortedL[j + 8 + q];
            const int s3 = sortedL[j + 12 + q];
            const float ns0 = norm_src[s0];
            const float ns1 = norm_src[s1];
            const float ns2 = norm_src[s2];
            const float ns3 = norm_src[s3];
            const uint4 v0 = *(const uint4*)&hs[(size_t)s0 * F + c8];
            const uint4 v1 = *(const uint4*)&hs[(size_t)s1 * F + c8];
            const uint4 v2 = *(const uint4*)&hs[(size_t)s2 * F + c8];
            const uint4 v3 = *(const uint4*)&hs[(size_t)s3 * F + c8];
            acc_bf8s(v0, ns0, acc);
            acc_bf8s(v1, ns1, acc);
            acc_bf8s(v2, ns2, acc);
            acc_bf8s(v3, ns3, acc);
        }
        for (; j + 8 <= end; j += 8) {
            const int s0 = sortedL[j + q];
            const int s1 = sortedL[j + 4 + q];
            const float ns0 = norm_src[s0];
            const float ns1 = norm_src[s1];
            const uint4 v0 = *(const uint4*)&hs[(size_t)s0 * F + c8];
            const uint4 v1 = *(const uint4*)&hs[(size_t)s1 * F + c8];
            acc_bf8s(v0, ns0, acc);
            acc_bf8s(v1, ns1, acc);
        }
        for (; j + 4 <= end; j += 4) {
            const int s = sortedL[j + q];
            const float ns = norm_src[s];
            const uint4 v = *(const uint4*)&hs[(size_t)s * F + c8];
            acc_bf8s(v, ns, acc);
        }
        if (j + q < end) {
            const int s = sortedL[j + q];
            const float ns = norm_src[s];
            const uint4 v = *(const uint4*)&hs[(size_t)s * F + c8];
            acc_bf8s(v, ns, acc);
        }
        #pragma unroll
        for (int k = 0; k < 8; ++k) {
            acc[k] += __shfl_xor(acc[k], 16);
            acc[k] += __shfl_xor(acc[k], 32);
        }

        const int n = nlo + nh;
        const float nd = rsqrtf((float)max(cnt[nh], 1));
        float pa = 0.f, pc = 0.f;
        #pragma unroll
        for (int k = 0; k < 8; ++k) {
            const float ok = fmaxf(acc[k] * nd + bb[k], 0.f);
            pa += ok * Vl[k].x;
            pc += ok * Vl[k].y;
        }
        #pragma unroll
        for (int m = 1; m <= 8; m <<= 1) {
            pa += __shfl_xor(pa, m);
            pc += __shfl_xor(pc, m);
        }
        if (l == 0) {
            const float ns = norm_src[n];
            uw[n] = make_float2(ns * pa, ns * pc);
        }
    }
}

// ---------------- layer-2 aggregation: bucket-parallel (8 threads/node) ----------------
__global__ __launch_bounds__(256, 8)
void ac_kernel(const float2* __restrict__ uw, const int* __restrict__ sorted_src,
               const int* __restrict__ offs, const int* __restrict__ ends,
               const float* __restrict__ norm_dst,
               float* __restrict__ A, float* __restrict__ C) {
    const int tid = threadIdx.x;
    const int n   = blockIdx.x * 32 + (tid >> 3);   // NN == NBUCK*32 exactly
    const int sub = tid & 7;
    const int beg = offs[n];
    const int end = ends[n];
    float sx = 0.f, sy = 0.f;
    for (int j = beg + sub; j < end; j += 8) {
        const float2 t = uw[sorted_src[j]];
        sx += t.x;
        sy += t.y;
    }
    sx += __shfl_xor(sx, 1); sy += __shfl_xor(sy, 1);
    sx += __shfl_xor(sx, 2); sy += __shfl_xor(sy, 2);
    sx += __shfl_xor(sx, 4); sy += __shfl_xor(sy, 4);
    if (sub == 0) {
        const float nd = norm_dst[n];
        A[n] = nd * sx;
        C[n] = nd * sy;
    }
}

// ---------------- edge scores (4-wide) ----------------
__global__ void score_kernel(const float* __restrict__ A, const float* __restrict__ C,
                             const int4* __restrict__ src4, const int4* __restrict__ dst4,
                             const float* __restrict__ consts, float4* __restrict__ out4,
                             int nE4) {
    const int i = blockIdx.x * blockDim.x + threadIdx.x;
    if (i < nE4) {
        const int4 s = src4[i];
        const int4 d = dst4[i];
        const float cc = consts[0];
        float4 o;
        o.x = 1.f / (1.f + __expf(-(A[s.x] + C[d.x] + cc)));
        o.y = 1.f / (1.f + __expf(-(A[s.y] + C[d.y] + cc)));
        o.z = 1.f / (1.f + __expf(-(A[s.z] + C[d.z] + cc)));
        o.w = 1.f / (1.f + __expf(-(A[s.w] + C[d.w] + cc)));
        out4[i] = o;
    }
}

extern "C" void kernel_launch(void* const* d_in, const int* in_sizes, int n_in,
                              void* d_out, int out_size, void* d_ws, size_t ws_size,
                              hipStream_t stream) {
    const float* x  = (const float*)d_in[0];
    const float* W1 = (const float*)d_in[1];
    const float* b1 = (const float*)d_in[2];
    const float* W2 = (const float*)d_in[3];
    const float* b2 = (const float*)d_in[4];
    const float* Wp = (const float*)d_in[5];
    const float* bp = (const float*)d_in[6];
    const int*   src = (const int*)d_in[7];
    const int*   dst = (const int*)d_in[8];
    float* out = (float*)d_out;

    float* ws        = (float*)d_ws;
    float* norm_src  = ws;                        // NPAD
    float* bufA      = ws + NPAD;                 // NPAD: A[]
    float* bufC      = ws + 2 * NPAD;             // NPAD: C[]
    float* norm_dst  = ws + 3 * NPAD;             // NPAD
    int*   offs      = (int*)(ws + 4 * NPAD);     // NPAD
    int*   ends      = offs + NPAD;               // NPAD
    int*   gCur      = ends + NPAD;               // NBUCK*GSTRIDE = 50000, pad 50176
    int*   gRegCur   = gCur + 50176;              // NREG*GSTRIDE = 784, pad 1024
    int*   gRegCurS  = gRegCur + 1024;            // NREG*GSTRIDE = 784, pad 1024
    float* consts    = (float*)(gRegCurS + 1024); // 16
    float2* V        = (float2*)(consts + 16);    // 128 float2
    float2* uw       = V + 128;                   // NN float2
    int*   srcPart   = (int*)(uw + NN);           // NBUCK*BCAPG ints (9.6 MB)
    unsigned short* hs_bf = (unsigned short*)(srcPart + (size_t)NBUCK * BCAPG);  // NN*F bf16
    int*   gRegion   = (int*)(hs_bf + (size_t)NN * F);          // NREG*RCAP ints (7.2 MB)
    unsigned short* gRegionS = (unsigned short*)(gRegion + (size_t)NREG * RCAP); // NREG*RCAP u16 (3.6 MB)

    // cursors + folded head weights
    setup_kernel<<<15, 256, 0, stream>>>(gCur, gRegCur, gRegCurS, W2, Wp, b2, bp, consts, V);

    // layer-1 MFMA GEMM overlapped with dual-stream coarse binning (no global atomics)
    gemm1_fill_kernel<<<NFILL + NGEMM, 256, 0, stream>>>(x, W1, hs_bf, src, dst,
                                                         gRegCur, gRegCurS, gRegion, gRegionS);

    // pass 2: regions -> fine 32-node buckets (coalesced) + per-region deg histogram -> norm_src
    pass2_kernel<<<NREG * P2J, 256, 0, stream>>>(gRegion, gRegionS, gRegCur, gRegCurS,
                                                 gCur, srcPart, norm_src);

    // per-bucket LDS sort + feature gather + folded layer-2 head
    gather_sort_kernel<<<NBUCK, 256, 0, stream>>>(hs_bf, srcPart, gCur, norm_src, b1,
                                                  V, uw, offs, ends, norm_dst);

    // layer-2 aggregation: bucket-parallel, 8 threads per node
    ac_kernel<<<NBUCK, 256, 0, stream>>>(uw, srcPart, offs, ends, norm_dst,
                                         bufA, bufC);

    // edge scores (NE divisible by 4)
    score_kernel<<<(NE / 4 + 255) / 256, 256, 0, stream>>>(bufA, bufC, (const int4*)src,
                                                           (const int4*)dst, consts,
                                                           (float4*)out, NE / 4);
}